// Round 8
// baseline (216.153 us; speedup 1.0000x reference)
//
#include <hip/hip_runtime.h>

typedef unsigned short u16;
typedef __attribute__((ext_vector_type(4))) float f32x4;
typedef __attribute__((ext_vector_type(8))) short bf16x8;
typedef __attribute__((ext_vector_type(4))) unsigned short u16x4;

#define NT 128          // K-tiles per block: 8 experts x 16

__device__ __forceinline__ u16 f2bf(float f) {
  union { float f; unsigned u; } v; v.f = f;
  unsigned r = v.u + 0x7FFFu + ((v.u >> 16) & 1u);
  return (u16)(r >> 16);
}

__device__ __forceinline__ f32x4 zero4() {
  f32x4 z; z.x = 0.f; z.y = 0.f; z.z = 0.f; z.w = 0.f; return z;
}

// ---- kernel 1: x (f32) -> xb2 bf16 FRAGMENT-MAJOR layout ----
// xb2[gb(256)][kt(16)][kk(2)][lane(64)][8elem]; granule g holds
// x[gb*16 + (lane&15)][kt*64 + kk*32 + (lane>>4)*8 + e]
__global__ __launch_bounds__(256) void k_cvt_x2(const float* __restrict__ x, u16* __restrict__ xb2) {
  int g = blockIdx.x * 256 + threadIdx.x;   // 524288 granules
  int lane = g & 63;
  int kk = (g >> 6) & 1;
  int kt = (g >> 7) & 15;
  int gb = g >> 11;
  int row = gb * 16 + (lane & 15);
  int k0 = kt * 64 + kk * 32 + (lane >> 4) * 8;
  const f32x4* src = (const f32x4*)(x + (size_t)row * 1024 + k0);
  f32x4 v0 = src[0], v1 = src[1];
  union { u16 u[8]; bf16x8 v; } o;
  o.u[0]=f2bf(v0.x); o.u[1]=f2bf(v0.y); o.u[2]=f2bf(v0.z); o.u[3]=f2bf(v0.w);
  o.u[4]=f2bf(v1.x); o.u[5]=f2bf(v1.y); o.u[6]=f2bf(v1.z); o.u[7]=f2bf(v1.w);
  ((bf16x8*)xb2)[g] = o.v;
}

// ---- kernel 2: W[m][k][n] f32 -> Wt[m][n][k] bf16 (64x64 LDS transpose) ----
__global__ __launch_bounds__(256) void k_tw(const float* __restrict__ W, u16* __restrict__ wt) {
  __shared__ float t[64][65];
  int bid = blockIdx.x;
  int e = bid >> 8, rem = bid & 255, kt = rem >> 4, nt = rem & 15;
  int tid = threadIdx.x;
  int c = tid & 63, r0 = tid >> 6;
  const float* src = W + (size_t)e * 1048576 + (size_t)(kt * 64) * 1024 + nt * 64;
  #pragma unroll
  for (int p = 0; p < 16; ++p) {
    int r = r0 + p * 4;
    t[r][c] = src[r * 1024 + c];
  }
  __syncthreads();
  u16* dst = wt + (size_t)e * 1048576 + (size_t)(nt * 64) * 1024 + kt * 64;
  #pragma unroll
  for (int p = 0; p < 16; ++p) {
    int r2 = r0 + p * 4;
    dst[r2 * 1024 + c] = f2bf(t[c][r2]);
  }
}

// ---- kernel 3: gates[b][m] = gu^2 / sum_m gu^2, gu = x@Wg + bg ----
__global__ __launch_bounds__(256) void k_gates(const float* __restrict__ x, const float* __restrict__ Wg,
                                               const float* __restrict__ bg, float* __restrict__ gates) {
  int wid = threadIdx.x >> 6, lane = threadIdx.x & 63;
  int b = blockIdx.x * 4 + wid;
  const float* xr = x + (size_t)b * 1024;
  float acc[16];
  #pragma unroll
  for (int m = 0; m < 16; ++m) acc[m] = 0.f;
  for (int i = lane; i < 1024; i += 64) {
    float xv = xr[i];
    const f32x4* wg = (const f32x4*)(Wg + (size_t)i * 16);
    #pragma unroll
    for (int q = 0; q < 4; ++q) {
      f32x4 w = wg[q];
      acc[q*4+0] += xv * w.x; acc[q*4+1] += xv * w.y;
      acc[q*4+2] += xv * w.z; acc[q*4+3] += xv * w.w;
    }
  }
  #pragma unroll
  for (int m = 0; m < 16; ++m) {
    #pragma unroll
    for (int off = 32; off > 0; off >>= 1)
      acc[m] += __shfl_xor(acc[m], off, 64);
  }
  float tot = 0.f, gp[16];
  #pragma unroll
  for (int m = 0; m < 16; ++m) { float gu = acc[m] + bg[m]; gp[m] = gu * gu; tot += gp[m]; }
  float inv = 1.f / tot;
  if (lane == 0) {
    #pragma unroll
    for (int m = 0; m < 16; ++m) gates[(size_t)b * 16 + m] = gp[m] * inv;
  }
}

// ---- kernel 4: fused MoE GEMM, 128x128 tile, 4 waves, A reg-dbuf issue-early, B LDS dbuf ----
#define GLL(srcaddr, ldsaddr) \
  __builtin_amdgcn_global_load_lds((const __attribute__((address_space(1))) void*)(srcaddr), \
                                   (__attribute__((address_space(3))) void*)(ldsaddr), 16, 0, 0)

// One K-tile: T = tile index, U = A-reg set in use, L = A-reg set to load (T+1), PF = prefetch valid
#define SUBITER(T, U, L, PF) do {                                              \
  int _t = (T);                                                                \
  bf16x8 cc[4];                                                                \
  cc[0] = *(const bf16x8*)&b0[pb0];                                            \
  cc[1] = *(const bf16x8*)&b0[pb0 + 1024];                                     \
  cc[2] = *(const bf16x8*)&b0[pb0 + 2048];                                     \
  cc[3] = *(const bf16x8*)&b0[pb0 + 3072];                                     \
  if (PF) {                                                                    \
    const u16* sb1 = bsrc + (size_t)((_t + 1) >> 4) * 1048576 + ((_t + 1) & 15) * 64; \
    GLL(sb1 + sg[0], b1 + ldd[0]); GLL(sb1 + sg[1], b1 + ldd[1]);              \
    GLL(sb1 + sg[2], b1 + ldd[2]); GLL(sb1 + sg[3], b1 + ldd[3]);              \
  }                                                                            \
  __builtin_amdgcn_sched_barrier(0);  /* pin GLLs before A loads (vmcnt order) */ \
  if (PF) {                                                                    \
    int ko = ((_t + 1) & 15) * 1024;                                           \
    av[L][0] = *(const bf16x8*)(ab0 + ko); av[L][4] = *(const bf16x8*)(ab0 + ko + 512); \
    av[L][1] = *(const bf16x8*)(ab1 + ko); av[L][5] = *(const bf16x8*)(ab1 + ko + 512); \
    av[L][2] = *(const bf16x8*)(ab2 + ko); av[L][6] = *(const bf16x8*)(ab2 + ko + 512); \
    av[L][3] = *(const bf16x8*)(ab3 + ko); av[L][7] = *(const bf16x8*)(ab3 + ko + 512); \
  }                                                                            \
  __builtin_amdgcn_s_setprio(1);                                               \
  _Pragma("unroll")                                                            \
  for (int mi = 0; mi < 4; ++mi)                                               \
    _Pragma("unroll")                                                          \
    for (int ni = 0; ni < 4; ++ni)                                             \
      acc[mi][ni] = __builtin_amdgcn_mfma_f32_16x16x32_bf16(av[U][mi], cc[ni], acc[mi][ni], 0,0,0); \
  cc[0] = *(const bf16x8*)&b0[pb1];                                            \
  cc[1] = *(const bf16x8*)&b0[pb1 + 1024];                                     \
  cc[2] = *(const bf16x8*)&b0[pb1 + 2048];                                     \
  cc[3] = *(const bf16x8*)&b0[pb1 + 3072];                                     \
  _Pragma("unroll")                                                            \
  for (int mi = 0; mi < 4; ++mi)                                               \
    _Pragma("unroll")                                                          \
    for (int ni = 0; ni < 4; ++ni)                                             \
      acc[mi][ni] = __builtin_amdgcn_mfma_f32_16x16x32_bf16(av[U][4 + mi], cc[ni], acc[mi][ni], 0,0,0); \
  __builtin_amdgcn_s_setprio(0);                                               \
  if ((_t & 15) == 15) {                                                       \
    int ml = _t >> 4;                                                          \
    float bvv[4];                                                              \
    _Pragma("unroll")                                                          \
    for (int ni = 0; ni < 4; ++ni) bvv[ni] = lbias[ml * 128 + wn * 64 + ni * 16 + lrow]; \
    _Pragma("unroll")                                                          \
    for (int mi = 0; mi < 4; ++mi) {                                           \
      f32x4 gv = *(const f32x4*)&lgat[ml * 128 + wm * 64 + mi * 16 + lk * 4];  \
      _Pragma("unroll")                                                        \
      for (int ni = 0; ni < 4; ++ni) {                                         \
        _Pragma("unroll")                                                      \
        for (int j = 0; j < 4; ++j) {                                          \
          float h = acc[mi][ni][j] + bvv[ni];                                  \
          h = fmaxf(h, 0.f);                                                   \
          oacc[mi][ni][j] += gv[j] * h;                                        \
        }                                                                      \
        acc[mi][ni] = zero4();                                                 \
      }                                                                        \
    }                                                                          \
  }                                                                            \
  if (PF) {                                                                    \
    /* outstanding: [B-GLL(t+1):4][A(t+1):8] -> drain B, keep A in flight */   \
    asm volatile("s_waitcnt vmcnt(8)" ::: "memory");                           \
    __builtin_amdgcn_s_barrier();                                              \
    __builtin_amdgcn_sched_barrier(0);                                         \
    u16* _tb = b0; b0 = b1; b1 = _tb;                                          \
  }                                                                            \
} while (0)

__global__ __launch_bounds__(256, 2)
void k_moe(const u16* __restrict__ xb2, const u16* __restrict__ wt,
           const float* __restrict__ gates, const float* __restrict__ bias,
           float* __restrict__ out0, float* __restrict__ p1out) {
  __shared__ __align__(16) u16 sB[2 * 8192];    // 2 x 128x64 bf16
  __shared__ float lgat[1024];                  // [8 experts][128 rows]
  __shared__ float lbias[1024];                 // [8 experts][128 cols]

  int tid = threadIdx.x;
  int bid = blockIdx.x;
  // XCD-chunked swizzle: 64 consecutive blocks per XCD -> 2 B-panels (4MB, fits L2)
  int swz = (bid & 7) * 64 + (bid >> 3);
  int btile = swz & 31;
  int pnl = swz >> 5;          // 0..15
  int ntile = pnl & 7;
  int grp = pnl >> 3;
  int brow0 = btile * 128;
  int ncol0 = ntile * 128;
  int mb = grp * 8;

  int wid = tid >> 6, lane = tid & 63;
  int wm = wid >> 1, wn = wid & 1;              // 2M x 2N wave grid, wave tile 64x64
  int lrow = lane & 15, lk = lane >> 4;
  int sw = lrow & 7;

  const u16* bsrc = wt + (size_t)mb * 1048576 + (size_t)ncol0 * 1024;

  // B stage offsets: 128x64 tile = 1024 granules of 16B; 4 GLL per thread
  int sg[4], ldd[4];
  #pragma unroll
  for (int it = 0; it < 4; ++it) {
    int idx = it * 256 + tid;
    int r = idx >> 3, s = idx & 7;
    sg[it] = r * 1024 + (s ^ (r & 7)) * 8;      // inverse-swizzled global src (elements)
    ldd[it] = (it * 256 + wid * 64) * 8;        // wave-uniform linear LDS dst (elements)
  }

  // B frag read offsets (swizzled granules)
  int baseB = (wn * 64 + lrow) * 64;
  int pb0 = baseB + ((0 + lk) ^ sw) * 8;   // kk=0
  int pb1 = baseB + ((4 + lk) ^ sw) * 8;   // kk=1

  // A fragment-major bases: row-block gb = btile*8 + wm*4 + mi
  const u16* ab0 = xb2 + (size_t)(btile * 8 + wm * 4 + 0) * 16384 + lane * 8;
  const u16* ab1 = ab0 + 16384;
  const u16* ab2 = ab0 + 32768;
  const u16* ab3 = ab0 + 49152;

  f32x4 acc[4][4], oacc[4][4];
  #pragma unroll
  for (int i = 0; i < 4; ++i)
    #pragma unroll
    for (int j = 0; j < 4; ++j) { acc[i][j] = zero4(); oacc[i][j] = zero4(); }

  u16 *b0 = sB, *b1 = sB + 8192;
  bf16x8 av[2][8];   // double-buffered A fragment sets (static indices only)

  // ---- prologue ----
  // gates/bias -> LDS first (isolated vmcnt(0), once)
  {
    float gt[4], bt[4];
    #pragma unroll
    for (int i = 0; i < 4; ++i) {
      int idx = i * 256 + tid;
      gt[i] = gates[(size_t)(brow0 + (idx & 127)) * 16 + mb + (idx >> 7)];
      bt[i] = bias[(size_t)(mb + (idx >> 7)) * 1024 + ncol0 + (idx & 127)];
    }
    asm volatile("s_waitcnt vmcnt(0)" ::: "memory");
    #pragma unroll
    for (int i = 0; i < 4; ++i) {
      int idx = i * 256 + tid;
      lgat[idx] = gt[i];
      lbias[idx] = bt[i];
    }
  }
  // GLL B(0), then A(0) -> av[0]
  GLL(bsrc + sg[0], b0 + ldd[0]); GLL(bsrc + sg[1], b0 + ldd[1]);
  GLL(bsrc + sg[2], b0 + ldd[2]); GLL(bsrc + sg[3], b0 + ldd[3]);
  __builtin_amdgcn_sched_barrier(0);
  av[0][0] = *(const bf16x8*)(ab0); av[0][4] = *(const bf16x8*)(ab0 + 512);
  av[0][1] = *(const bf16x8*)(ab1); av[0][5] = *(const bf16x8*)(ab1 + 512);
  av[0][2] = *(const bf16x8*)(ab2); av[0][6] = *(const bf16x8*)(ab2 + 512);
  av[0][3] = *(const bf16x8*)(ab3); av[0][7] = *(const bf16x8*)(ab3 + 512);
  // drain B(0) GLLs (oldest 4), keep A(0) in flight (auto-waited at first MFMA use)
  asm volatile("s_waitcnt vmcnt(8)" ::: "memory");
  __builtin_amdgcn_s_barrier();
  __builtin_amdgcn_sched_barrier(0);

  // ---- main loop: x2 unrolled for static A-set alternation ----
  for (int u = 0; u < NT / 2 - 1; ++u) {
    SUBITER(2 * u,     0, 1, true);
    SUBITER(2 * u + 1, 1, 0, true);
  }
  SUBITER(NT - 2, 0, 1, true);
  SUBITER(NT - 1, 1, 0, false);

  float* op = grp ? p1out : out0;
  #pragma unroll
  for (int mi = 0; mi < 4; ++mi)
    #pragma unroll
    for (int j = 0; j < 4; ++j) {
      int row = brow0 + wm * 64 + mi * 16 + lk * 4 + j;
      #pragma unroll
      for (int ni = 0; ni < 4; ++ni) {
        int col = ncol0 + wn * 64 + ni * 16 + lrow;
        op[(size_t)row * 1024 + col] = oacc[mi][ni][j];
      }
    }
}

// ---- kernel 5: out += p1 ----
__global__ __launch_bounds__(256) void k_add(float* __restrict__ out, const float* __restrict__ p1) {
  int i = blockIdx.x * 256 + threadIdx.x;
  f32x4 a = ((const f32x4*)out)[i];
  f32x4 b = ((const f32x4*)p1)[i];
  ((f32x4*)out)[i] = a + b;
}

extern "C" void kernel_launch(void* const* d_in, const int* in_sizes, int n_in,
                              void* d_out, int out_size, void* d_ws, size_t ws_size,
                              hipStream_t stream) {
  const float* x  = (const float*)d_in[0];   // [4096][1024]
  const float* W  = (const float*)d_in[1];   // [16][1024][1024]
  const float* b  = (const float*)d_in[2];   // [16][1024]
  const float* Wg = (const float*)d_in[3];   // [1024][16]
  const float* bg = (const float*)d_in[4];   // [16]
  float* out = (float*)d_out;                // [4096][1024]

  char* ws = (char*)d_ws;
  u16* xb2    = (u16*)ws;                      // 8,388,608 B (fragment-major)
  u16* wt     = (u16*)(ws + 8388608);          // 33,554,432 B
  float* gts  = (float*)(ws + 41943040);       // 262,144 B
  float* p1   = (float*)(ws + 42205184);       // 16,777,216 B

  k_cvt_x2<<<2048, 256, 0, stream>>>(x, xb2);
  k_tw<<<4096, 256, 0, stream>>>(W, wt);
  k_gates<<<1024, 256, 0, stream>>>(x, Wg, bg, gts);
  k_moe<<<512, 256, 0, stream>>>(xb2, wt, gts, b, out, p1);
  k_add<<<4096, 256, 0, stream>>>(out, p1);
}

// Round 9
// 200.688 us; speedup vs baseline: 1.0771x; 1.0771x over previous
//
#include <hip/hip_runtime.h>

typedef unsigned short u16;
typedef __attribute__((ext_vector_type(4))) float f32x4;
typedef __attribute__((ext_vector_type(8))) short bf16x8;
typedef __attribute__((ext_vector_type(4))) unsigned short u16x4;

#define NT 128          // K-tiles per block: 8 experts x 16

__device__ __forceinline__ u16 f2bf(float f) {
  union { float f; unsigned u; } v; v.f = f;
  unsigned r = v.u + 0x7FFFu + ((v.u >> 16) & 1u);
  return (u16)(r >> 16);
}

__device__ __forceinline__ f32x4 zero4() {
  f32x4 z; z.x = 0.f; z.y = 0.f; z.z = 0.f; z.w = 0.f; return z;
}

// ---- kernel 1: x (f32) -> xb2 bf16 FRAGMENT-MAJOR layout ----
// xb2[gb(256)][kt(16)][kk(2)][lane(64)][8elem]; granule g holds
// x[gb*16 + (lane&15)][kt*64 + kk*32 + (lane>>4)*8 + e]
__global__ __launch_bounds__(256) void k_cvt_x2(const float* __restrict__ x, u16* __restrict__ xb2) {
  int g = blockIdx.x * 256 + threadIdx.x;   // 524288 granules
  int lane = g & 63;
  int kk = (g >> 6) & 1;
  int kt = (g >> 7) & 15;
  int gb = g >> 11;
  int row = gb * 16 + (lane & 15);
  int k0 = kt * 64 + kk * 32 + (lane >> 4) * 8;
  const f32x4* src = (const f32x4*)(x + (size_t)row * 1024 + k0);
  f32x4 v0 = src[0], v1 = src[1];
  union { u16 u[8]; bf16x8 v; } o;
  o.u[0]=f2bf(v0.x); o.u[1]=f2bf(v0.y); o.u[2]=f2bf(v0.z); o.u[3]=f2bf(v0.w);
  o.u[4]=f2bf(v1.x); o.u[5]=f2bf(v1.y); o.u[6]=f2bf(v1.z); o.u[7]=f2bf(v1.w);
  ((bf16x8*)xb2)[g] = o.v;
}

// ---- kernel 2: W[m][k][n] f32 -> Wt[m][n][k] bf16 (64x64 LDS transpose) ----
__global__ __launch_bounds__(256) void k_tw(const float* __restrict__ W, u16* __restrict__ wt) {
  __shared__ float t[64][65];
  int bid = blockIdx.x;
  int e = bid >> 8, rem = bid & 255, kt = rem >> 4, nt = rem & 15;
  int tid = threadIdx.x;
  int c = tid & 63, r0 = tid >> 6;
  const float* src = W + (size_t)e * 1048576 + (size_t)(kt * 64) * 1024 + nt * 64;
  #pragma unroll
  for (int p = 0; p < 16; ++p) {
    int r = r0 + p * 4;
    t[r][c] = src[r * 1024 + c];
  }
  __syncthreads();
  u16* dst = wt + (size_t)e * 1048576 + (size_t)(nt * 64) * 1024 + kt * 64;
  #pragma unroll
  for (int p = 0; p < 16; ++p) {
    int r2 = r0 + p * 4;
    dst[r2 * 1024 + c] = f2bf(t[c][r2]);
  }
}

// ---- kernel 3: gates[b][m] = gu^2 / sum_m gu^2, gu = x@Wg + bg ----
__global__ __launch_bounds__(256) void k_gates(const float* __restrict__ x, const float* __restrict__ Wg,
                                               const float* __restrict__ bg, float* __restrict__ gates) {
  int wid = threadIdx.x >> 6, lane = threadIdx.x & 63;
  int b = blockIdx.x * 4 + wid;
  const float* xr = x + (size_t)b * 1024;
  float acc[16];
  #pragma unroll
  for (int m = 0; m < 16; ++m) acc[m] = 0.f;
  for (int i = lane; i < 1024; i += 64) {
    float xv = xr[i];
    const f32x4* wg = (const f32x4*)(Wg + (size_t)i * 16);
    #pragma unroll
    for (int q = 0; q < 4; ++q) {
      f32x4 w = wg[q];
      acc[q*4+0] += xv * w.x; acc[q*4+1] += xv * w.y;
      acc[q*4+2] += xv * w.z; acc[q*4+3] += xv * w.w;
    }
  }
  #pragma unroll
  for (int m = 0; m < 16; ++m) {
    #pragma unroll
    for (int off = 32; off > 0; off >>= 1)
      acc[m] += __shfl_xor(acc[m], off, 64);
  }
  float tot = 0.f, gp[16];
  #pragma unroll
  for (int m = 0; m < 16; ++m) { float gu = acc[m] + bg[m]; gp[m] = gu * gu; tot += gp[m]; }
  float inv = 1.f / tot;
  if (lane == 0) {
    #pragma unroll
    for (int m = 0; m < 16; ++m) gates[(size_t)b * 16 + m] = gp[m] * inv;
  }
}

// ---- kernel 4: fused MoE GEMM, 128x128 tile, 4 waves, A reg-dbuf issue-early, B LDS dbuf ----
#define GLL(srcaddr, ldsaddr) \
  __builtin_amdgcn_global_load_lds((const __attribute__((address_space(1))) void*)(srcaddr), \
                                   (__attribute__((address_space(3))) void*)(ldsaddr), 16, 0, 0)

// One K-tile: T = tile index, U = A-reg set in use, L = A-reg set to load (T+1), PF = prefetch valid
#define SUBITER(T, U, L, PF) do {                                              \
  int _t = (T);                                                                \
  bf16x8 cc[4];                                                                \
  cc[0] = *(const bf16x8*)&b0[pb0];                                            \
  cc[1] = *(const bf16x8*)&b0[pb0 + 1024];                                     \
  cc[2] = *(const bf16x8*)&b0[pb0 + 2048];                                     \
  cc[3] = *(const bf16x8*)&b0[pb0 + 3072];                                     \
  if (PF) {                                                                    \
    const u16* sb1 = bsrc + (size_t)((_t + 1) >> 4) * 1048576 + ((_t + 1) & 15) * 64; \
    GLL(sb1 + sg[0], b1 + ldd[0]); GLL(sb1 + sg[1], b1 + ldd[1]);              \
    GLL(sb1 + sg[2], b1 + ldd[2]); GLL(sb1 + sg[3], b1 + ldd[3]);              \
  }                                                                            \
  __builtin_amdgcn_sched_barrier(0);  /* pin GLLs before A loads (vmcnt order) */ \
  if (PF) {                                                                    \
    int ko = ((_t + 1) & 15) * 1024;                                           \
    av[L][0] = *(const bf16x8*)(ab0 + ko); av[L][4] = *(const bf16x8*)(ab0 + ko + 512); \
    av[L][1] = *(const bf16x8*)(ab1 + ko); av[L][5] = *(const bf16x8*)(ab1 + ko + 512); \
    av[L][2] = *(const bf16x8*)(ab2 + ko); av[L][6] = *(const bf16x8*)(ab2 + ko + 512); \
    av[L][3] = *(const bf16x8*)(ab3 + ko); av[L][7] = *(const bf16x8*)(ab3 + ko + 512); \
  }                                                                            \
  __builtin_amdgcn_s_setprio(1);                                               \
  _Pragma("unroll")                                                            \
  for (int mi = 0; mi < 4; ++mi)                                               \
    _Pragma("unroll")                                                          \
    for (int ni = 0; ni < 4; ++ni)                                             \
      acc[mi][ni] = __builtin_amdgcn_mfma_f32_16x16x32_bf16(av[U][mi], cc[ni], acc[mi][ni], 0,0,0); \
  cc[0] = *(const bf16x8*)&b0[pb1];                                            \
  cc[1] = *(const bf16x8*)&b0[pb1 + 1024];                                     \
  cc[2] = *(const bf16x8*)&b0[pb1 + 2048];                                     \
  cc[3] = *(const bf16x8*)&b0[pb1 + 3072];                                     \
  _Pragma("unroll")                                                            \
  for (int mi = 0; mi < 4; ++mi)                                               \
    _Pragma("unroll")                                                          \
    for (int ni = 0; ni < 4; ++ni)                                             \
      acc[mi][ni] = __builtin_amdgcn_mfma_f32_16x16x32_bf16(av[U][4 + mi], cc[ni], acc[mi][ni], 0,0,0); \
  __builtin_amdgcn_s_setprio(0);                                               \
  if ((_t & 15) == 15) {                                                       \
    int ml = _t >> 4;                                                          \
    float bvv[4];                                                              \
    _Pragma("unroll")                                                          \
    for (int ni = 0; ni < 4; ++ni) bvv[ni] = lbias[ml * 128 + wn * 64 + ni * 16 + lrow]; \
    _Pragma("unroll")                                                          \
    for (int mi = 0; mi < 4; ++mi) {                                           \
      f32x4 gv = *(const f32x4*)&lgat[ml * 128 + wm * 64 + mi * 16 + lk * 4];  \
      _Pragma("unroll")                                                        \
      for (int ni = 0; ni < 4; ++ni) {                                         \
        _Pragma("unroll")                                                      \
        for (int j = 0; j < 4; ++j) {                                          \
          float h = acc[mi][ni][j] + bvv[ni];                                  \
          h = fmaxf(h, 0.f);                                                   \
          oacc[mi][ni][j] += gv[j] * h;                                        \
        }                                                                      \
        acc[mi][ni] = zero4();                                                 \
      }                                                                        \
    }                                                                          \
  }                                                                            \
  if (PF) {                                                                    \
    /* outstanding: [B-GLL(t+1):4][A(t+1):8] -> drain B, keep A in flight */   \
    asm volatile("s_waitcnt vmcnt(8)" ::: "memory");                           \
    __builtin_amdgcn_s_barrier();                                              \
    __builtin_amdgcn_sched_barrier(0);                                         \
    u16* _tb = b0; b0 = b1; b1 = _tb;                                          \
  }                                                                            \
} while (0)

__global__ __launch_bounds__(256, 2)
void k_moe(const u16* __restrict__ xb2, const u16* __restrict__ wt,
           const float* __restrict__ gates, const float* __restrict__ bias,
           float* __restrict__ out0, float* __restrict__ p1out) {
  __shared__ __align__(16) u16 sB[2 * 8192];    // 2 x 128x64 bf16
  __shared__ float lgat[1024];                  // [8 experts][128 rows]
  __shared__ float lbias[1024];                 // [8 experts][128 cols]

  int tid = threadIdx.x;
  int bid = blockIdx.x;
  // btile-grouped XCD swizzle: XCD x (= bid&7) owns btiles {4x..4x+3} across all 16 panels.
  // Per-XCD A working set = 4 x 256KB = 1MB -> L2-resident; A-frag loads become L2 hits.
  // Consecutive 4 blocks per XCD share one B panel (partial L2 reuse); B latency is
  // covered by counted-vmcnt GLL anyway.
  int btile = (bid & 7) * 4 + ((bid >> 3) & 3);
  int pnl = bid >> 5;          // 0..15
  int ntile = pnl & 7;
  int grp = pnl >> 3;
  int brow0 = btile * 128;
  int ncol0 = ntile * 128;
  int mb = grp * 8;

  int wid = tid >> 6, lane = tid & 63;
  int wm = wid >> 1, wn = wid & 1;              // 2M x 2N wave grid, wave tile 64x64
  int lrow = lane & 15, lk = lane >> 4;
  int sw = lrow & 7;

  const u16* bsrc = wt + (size_t)mb * 1048576 + (size_t)ncol0 * 1024;

  // B stage offsets: 128x64 tile = 1024 granules of 16B; 4 GLL per thread
  int sg[4], ldd[4];
  #pragma unroll
  for (int it = 0; it < 4; ++it) {
    int idx = it * 256 + tid;
    int r = idx >> 3, s = idx & 7;
    sg[it] = r * 1024 + (s ^ (r & 7)) * 8;      // inverse-swizzled global src (elements)
    ldd[it] = (it * 256 + wid * 64) * 8;        // wave-uniform linear LDS dst (elements)
  }

  // B frag read offsets (swizzled granules)
  int baseB = (wn * 64 + lrow) * 64;
  int pb0 = baseB + ((0 + lk) ^ sw) * 8;   // kk=0
  int pb1 = baseB + ((4 + lk) ^ sw) * 8;   // kk=1

  // A fragment-major bases: row-block gb = btile*8 + wm*4 + mi
  const u16* ab0 = xb2 + (size_t)(btile * 8 + wm * 4 + 0) * 16384 + lane * 8;
  const u16* ab1 = ab0 + 16384;
  const u16* ab2 = ab0 + 32768;
  const u16* ab3 = ab0 + 49152;

  f32x4 acc[4][4], oacc[4][4];
  #pragma unroll
  for (int i = 0; i < 4; ++i)
    #pragma unroll
    for (int j = 0; j < 4; ++j) { acc[i][j] = zero4(); oacc[i][j] = zero4(); }

  u16 *b0 = sB, *b1 = sB + 8192;
  bf16x8 av[2][8];   // double-buffered A fragment sets (static indices only)

  // ---- prologue ----
  // gates/bias -> LDS first (isolated vmcnt(0), once)
  {
    float gt[4], bt[4];
    #pragma unroll
    for (int i = 0; i < 4; ++i) {
      int idx = i * 256 + tid;
      gt[i] = gates[(size_t)(brow0 + (idx & 127)) * 16 + mb + (idx >> 7)];
      bt[i] = bias[(size_t)(mb + (idx >> 7)) * 1024 + ncol0 + (idx & 127)];
    }
    asm volatile("s_waitcnt vmcnt(0)" ::: "memory");
    #pragma unroll
    for (int i = 0; i < 4; ++i) {
      int idx = i * 256 + tid;
      lgat[idx] = gt[i];
      lbias[idx] = bt[i];
    }
  }
  // GLL B(0), then A(0) -> av[0]
  GLL(bsrc + sg[0], b0 + ldd[0]); GLL(bsrc + sg[1], b0 + ldd[1]);
  GLL(bsrc + sg[2], b0 + ldd[2]); GLL(bsrc + sg[3], b0 + ldd[3]);
  __builtin_amdgcn_sched_barrier(0);
  av[0][0] = *(const bf16x8*)(ab0); av[0][4] = *(const bf16x8*)(ab0 + 512);
  av[0][1] = *(const bf16x8*)(ab1); av[0][5] = *(const bf16x8*)(ab1 + 512);
  av[0][2] = *(const bf16x8*)(ab2); av[0][6] = *(const bf16x8*)(ab2 + 512);
  av[0][3] = *(const bf16x8*)(ab3); av[0][7] = *(const bf16x8*)(ab3 + 512);
  // drain B(0) GLLs (oldest 4), keep A(0) in flight (auto-waited at first MFMA use)
  asm volatile("s_waitcnt vmcnt(8)" ::: "memory");
  __builtin_amdgcn_s_barrier();
  __builtin_amdgcn_sched_barrier(0);

  // ---- main loop: x2 unrolled for static A-set alternation ----
  for (int u = 0; u < NT / 2 - 1; ++u) {
    SUBITER(2 * u,     0, 1, true);
    SUBITER(2 * u + 1, 1, 0, true);
  }
  SUBITER(NT - 2, 0, 1, true);
  SUBITER(NT - 1, 1, 0, false);

  float* op = grp ? p1out : out0;
  #pragma unroll
  for (int mi = 0; mi < 4; ++mi)
    #pragma unroll
    for (int j = 0; j < 4; ++j) {
      int row = brow0 + wm * 64 + mi * 16 + lk * 4 + j;
      #pragma unroll
      for (int ni = 0; ni < 4; ++ni) {
        int col = ncol0 + wn * 64 + ni * 16 + lrow;
        op[(size_t)row * 1024 + col] = oacc[mi][ni][j];
      }
    }
}

// ---- kernel 5: out += p1 ----
__global__ __launch_bounds__(256) void k_add(float* __restrict__ out, const float* __restrict__ p1) {
  int i = blockIdx.x * 256 + threadIdx.x;
  f32x4 a = ((const f32x4*)out)[i];
  f32x4 b = ((const f32x4*)p1)[i];
  ((f32x4*)out)[i] = a + b;
}

extern "C" void kernel_launch(void* const* d_in, const int* in_sizes, int n_in,
                              void* d_out, int out_size, void* d_ws, size_t ws_size,
                              hipStream_t stream) {
  const float* x  = (const float*)d_in[0];   // [4096][1024]
  const float* W  = (const float*)d_in[1];   // [16][1024][1024]
  const float* b  = (const float*)d_in[2];   // [16][1024]
  const float* Wg = (const float*)d_in[3];   // [1024][16]
  const float* bg = (const float*)d_in[4];   // [16]
  float* out = (float*)d_out;                // [4096][1024]

  char* ws = (char*)d_ws;
  u16* xb2    = (u16*)ws;                      // 8,388,608 B (fragment-major)
  u16* wt     = (u16*)(ws + 8388608);          // 33,554,432 B
  float* gts  = (float*)(ws + 41943040);       // 262,144 B
  float* p1   = (float*)(ws + 42205184);       // 16,777,216 B

  k_cvt_x2<<<2048, 256, 0, stream>>>(x, xb2);
  k_tw<<<4096, 256, 0, stream>>>(W, wt);
  k_gates<<<1024, 256, 0, stream>>>(x, Wg, bg, gts);
  k_moe<<<512, 256, 0, stream>>>(xb2, wt, gts, b, out, p1);
  k_add<<<4096, 256, 0, stream>>>(out, p1);
}

// Round 10
// 199.715 us; speedup vs baseline: 1.0823x; 1.0049x over previous
//
#include <hip/hip_runtime.h>

typedef unsigned short u16;
typedef __attribute__((ext_vector_type(4))) float f32x4;
typedef __attribute__((ext_vector_type(8))) short bf16x8;
typedef __attribute__((ext_vector_type(4))) unsigned short u16x4;

#define NT 128          // K-tiles per block: 8 experts x 16

__device__ __forceinline__ u16 f2bf(float f) {
  union { float f; unsigned u; } v; v.f = f;
  unsigned r = v.u + 0x7FFFu + ((v.u >> 16) & 1u);
  return (u16)(r >> 16);
}

__device__ __forceinline__ f32x4 zero4() {
  f32x4 z; z.x = 0.f; z.y = 0.f; z.z = 0.f; z.w = 0.f; return z;
}

// ---- kernel 1: x (f32) -> xb2 bf16 FRAGMENT-MAJOR layout ----
// xb2[gb(256)][kt(16)][kk(2)][lane(64)][8elem]; granule g holds
// x[gb*16 + (lane&15)][kt*64 + kk*32 + (lane>>4)*8 + e]
__global__ __launch_bounds__(256) void k_cvt_x2(const float* __restrict__ x, u16* __restrict__ xb2) {
  int g = blockIdx.x * 256 + threadIdx.x;   // 524288 granules
  int lane = g & 63;
  int kk = (g >> 6) & 1;
  int kt = (g >> 7) & 15;
  int gb = g >> 11;
  int row = gb * 16 + (lane & 15);
  int k0 = kt * 64 + kk * 32 + (lane >> 4) * 8;
  const f32x4* src = (const f32x4*)(x + (size_t)row * 1024 + k0);
  f32x4 v0 = src[0], v1 = src[1];
  union { u16 u[8]; bf16x8 v; } o;
  o.u[0]=f2bf(v0.x); o.u[1]=f2bf(v0.y); o.u[2]=f2bf(v0.z); o.u[3]=f2bf(v0.w);
  o.u[4]=f2bf(v1.x); o.u[5]=f2bf(v1.y); o.u[6]=f2bf(v1.z); o.u[7]=f2bf(v1.w);
  ((bf16x8*)xb2)[g] = o.v;
}

// ---- kernel 2: W[m][k][n] f32 -> Wt[m][n][k] bf16 (64x64 LDS transpose) ----
__global__ __launch_bounds__(256) void k_tw(const float* __restrict__ W, u16* __restrict__ wt) {
  __shared__ float t[64][65];
  int bid = blockIdx.x;
  int e = bid >> 8, rem = bid & 255, kt = rem >> 4, nt = rem & 15;
  int tid = threadIdx.x;
  int c = tid & 63, r0 = tid >> 6;
  const float* src = W + (size_t)e * 1048576 + (size_t)(kt * 64) * 1024 + nt * 64;
  #pragma unroll
  for (int p = 0; p < 16; ++p) {
    int r = r0 + p * 4;
    t[r][c] = src[r * 1024 + c];
  }
  __syncthreads();
  u16* dst = wt + (size_t)e * 1048576 + (size_t)(nt * 64) * 1024 + kt * 64;
  #pragma unroll
  for (int p = 0; p < 16; ++p) {
    int r2 = r0 + p * 4;
    dst[r2 * 1024 + c] = f2bf(t[c][r2]);
  }
}

// ---- kernel 3: gates[b][m] = gu^2 / sum_m gu^2, gu = x@Wg + bg ----
__global__ __launch_bounds__(256) void k_gates(const float* __restrict__ x, const float* __restrict__ Wg,
                                               const float* __restrict__ bg, float* __restrict__ gates) {
  int wid = threadIdx.x >> 6, lane = threadIdx.x & 63;
  int b = blockIdx.x * 4 + wid;
  const float* xr = x + (size_t)b * 1024;
  float acc[16];
  #pragma unroll
  for (int m = 0; m < 16; ++m) acc[m] = 0.f;
  for (int i = lane; i < 1024; i += 64) {
    float xv = xr[i];
    const f32x4* wg = (const f32x4*)(Wg + (size_t)i * 16);
    #pragma unroll
    for (int q = 0; q < 4; ++q) {
      f32x4 w = wg[q];
      acc[q*4+0] += xv * w.x; acc[q*4+1] += xv * w.y;
      acc[q*4+2] += xv * w.z; acc[q*4+3] += xv * w.w;
    }
  }
  #pragma unroll
  for (int m = 0; m < 16; ++m) {
    #pragma unroll
    for (int off = 32; off > 0; off >>= 1)
      acc[m] += __shfl_xor(acc[m], off, 64);
  }
  float tot = 0.f, gp[16];
  #pragma unroll
  for (int m = 0; m < 16; ++m) { float gu = acc[m] + bg[m]; gp[m] = gu * gu; tot += gp[m]; }
  float inv = 1.f / tot;
  if (lane == 0) {
    #pragma unroll
    for (int m = 0; m < 16; ++m) gates[(size_t)b * 16 + m] = gp[m] * inv;
  }
}

// ---- kernel 4: fused MoE GEMM, 128x128 tile, 4 waves, A reg-dbuf, B LDS 3-buf depth-2 ----
#define GLL(srcaddr, ldsaddr) \
  __builtin_amdgcn_global_load_lds((const __attribute__((address_space(1))) void*)(srcaddr), \
                                   (__attribute__((address_space(3))) void*)(ldsaddr), 16, 0, 0)

// One K-tile. T = tile idx, U = A-reg set in use, L = A-reg set to load (T+1),
// PF2 = issue GLL B(T+2) into b2, PFA = load A(T+1).
// vmcnt ledger (steady state): issue order ...[B(t+1):4][A(t):8][B(t+2):4][A(t+1):8].
// MFMA's auto-wait for A(t) = vmcnt(12), which transitively completes B(t+1) -> b1
// is ready for the next tile; B gets 2 tiles of flight, A gets 1.
#define SUBITER(T, U, L, PF2, PFA) do {                                        \
  int _t = (T);                                                                \
  bf16x8 cc[4];                                                                \
  cc[0] = *(const bf16x8*)&b0[pb0];                                            \
  cc[1] = *(const bf16x8*)&b0[pb0 + 1024];                                     \
  cc[2] = *(const bf16x8*)&b0[pb0 + 2048];                                     \
  cc[3] = *(const bf16x8*)&b0[pb0 + 3072];                                     \
  if (PF2) {                                                                   \
    const u16* sb2 = bsrc + (size_t)((_t + 2) >> 4) * 1048576 + ((_t + 2) & 15) * 64; \
    GLL(sb2 + sg[0], b2 + ldd[0]); GLL(sb2 + sg[1], b2 + ldd[1]);              \
    GLL(sb2 + sg[2], b2 + ldd[2]); GLL(sb2 + sg[3], b2 + ldd[3]);              \
  }                                                                            \
  __builtin_amdgcn_sched_barrier(0);  /* pin GLLs before A loads (vmcnt order) */ \
  if (PFA) {                                                                   \
    int ko = ((_t + 1) & 15) * 1024;                                           \
    av[L][0] = *(const bf16x8*)(ab0 + ko); av[L][4] = *(const bf16x8*)(ab0 + ko + 512); \
    av[L][1] = *(const bf16x8*)(ab1 + ko); av[L][5] = *(const bf16x8*)(ab1 + ko + 512); \
    av[L][2] = *(const bf16x8*)(ab2 + ko); av[L][6] = *(const bf16x8*)(ab2 + ko + 512); \
    av[L][3] = *(const bf16x8*)(ab3 + ko); av[L][7] = *(const bf16x8*)(ab3 + ko + 512); \
  }                                                                            \
  __builtin_amdgcn_s_setprio(1);                                               \
  _Pragma("unroll")                                                            \
  for (int mi = 0; mi < 4; ++mi)                                               \
    _Pragma("unroll")                                                          \
    for (int ni = 0; ni < 4; ++ni)                                             \
      acc[mi][ni] = __builtin_amdgcn_mfma_f32_16x16x32_bf16(av[U][mi], cc[ni], acc[mi][ni], 0,0,0); \
  cc[0] = *(const bf16x8*)&b0[pb1];                                            \
  cc[1] = *(const bf16x8*)&b0[pb1 + 1024];                                     \
  cc[2] = *(const bf16x8*)&b0[pb1 + 2048];                                     \
  cc[3] = *(const bf16x8*)&b0[pb1 + 3072];                                     \
  _Pragma("unroll")                                                            \
  for (int mi = 0; mi < 4; ++mi)                                               \
    _Pragma("unroll")                                                          \
    for (int ni = 0; ni < 4; ++ni)                                             \
      acc[mi][ni] = __builtin_amdgcn_mfma_f32_16x16x32_bf16(av[U][4 + mi], cc[ni], acc[mi][ni], 0,0,0); \
  __builtin_amdgcn_s_setprio(0);                                               \
  if ((_t & 15) == 15) {                                                       \
    int ml = _t >> 4;                                                          \
    float bvv[4];                                                              \
    _Pragma("unroll")                                                          \
    for (int ni = 0; ni < 4; ++ni) bvv[ni] = lbias[ml * 128 + wn * 64 + ni * 16 + lrow]; \
    _Pragma("unroll")                                                          \
    for (int mi = 0; mi < 4; ++mi) {                                           \
      f32x4 gv = *(const f32x4*)&lgat[ml * 128 + wm * 64 + mi * 16 + lk * 4];  \
      _Pragma("unroll")                                                        \
      for (int ni = 0; ni < 4; ++ni) {                                         \
        _Pragma("unroll")                                                      \
        for (int j = 0; j < 4; ++j) {                                          \
          float h = acc[mi][ni][j] + bvv[ni];                                  \
          h = fmaxf(h, 0.f);                                                   \
          oacc[mi][ni][j] += gv[j] * h;                                        \
        }                                                                      \
        acc[mi][ni] = zero4();                                                 \
      }                                                                        \
    }                                                                          \
  }                                                                            \
  if (_t < NT - 1) {                                                           \
    /* steady state: outstanding = [B(t+2):4][A(t+1):8] -> no-op; tails: over-drain ok */ \
    asm volatile("s_waitcnt vmcnt(12)" ::: "memory");                          \
    __builtin_amdgcn_s_barrier();                                              \
    __builtin_amdgcn_sched_barrier(0);                                         \
    u16* _tb = b0; b0 = b1; b1 = b2; b2 = _tb;                                 \
  }                                                                            \
} while (0)

__global__ __launch_bounds__(256, 2)
void k_moe(const u16* __restrict__ xb2, const u16* __restrict__ wt,
           const float* __restrict__ gates, const float* __restrict__ bias,
           float* __restrict__ out0, float* __restrict__ p1out) {
  __shared__ __align__(16) u16 sB[3 * 8192];    // 3 x 128x64 bf16
  __shared__ float lgat[1024];                  // [8 experts][128 rows]
  __shared__ float lbias[1024];                 // [8 experts][128 cols]

  int tid = threadIdx.x;
  int bid = blockIdx.x;
  // btile-grouped XCD swizzle: XCD x (= bid&7) owns btiles {4x..4x+3} across all 16 panels.
  // Per-XCD A working set = 4 x 256KB = 1MB -> L2-resident (A-frag loads are the
  // latency-SENSITIVE path). B loses panel affinity but flows through depth-2
  // counted-vmcnt GLL (latency-TOLERANT).
  int btile = (bid & 7) * 4 + ((bid >> 3) & 3);
  int pnl = bid >> 5;          // 0..15
  int ntile = pnl & 7;
  int grp = pnl >> 3;
  int brow0 = btile * 128;
  int ncol0 = ntile * 128;
  int mb = grp * 8;

  int wid = tid >> 6, lane = tid & 63;
  int wm = wid >> 1, wn = wid & 1;              // 2M x 2N wave grid, wave tile 64x64
  int lrow = lane & 15, lk = lane >> 4;
  int sw = lrow & 7;

  const u16* bsrc = wt + (size_t)mb * 1048576 + (size_t)ncol0 * 1024;

  // B stage offsets: 128x64 tile = 1024 granules of 16B; 4 GLL per thread
  int sg[4], ldd[4];
  #pragma unroll
  for (int it = 0; it < 4; ++it) {
    int idx = it * 256 + tid;
    int r = idx >> 3, s = idx & 7;
    sg[it] = r * 1024 + (s ^ (r & 7)) * 8;      // inverse-swizzled global src (elements)
    ldd[it] = (it * 256 + wid * 64) * 8;        // wave-uniform linear LDS dst (elements)
  }

  // B frag read offsets (swizzled granules)
  int baseB = (wn * 64 + lrow) * 64;
  int pb0 = baseB + ((0 + lk) ^ sw) * 8;   // kk=0
  int pb1 = baseB + ((4 + lk) ^ sw) * 8;   // kk=1

  // A fragment-major bases: row-block gb = btile*8 + wm*4 + mi
  const u16* ab0 = xb2 + (size_t)(btile * 8 + wm * 4 + 0) * 16384 + lane * 8;
  const u16* ab1 = ab0 + 16384;
  const u16* ab2 = ab0 + 32768;
  const u16* ab3 = ab0 + 49152;

  f32x4 acc[4][4], oacc[4][4];
  #pragma unroll
  for (int i = 0; i < 4; ++i)
    #pragma unroll
    for (int j = 0; j < 4; ++j) { acc[i][j] = zero4(); oacc[i][j] = zero4(); }

  u16 *b0 = sB, *b1 = sB + 8192, *b2 = sB + 16384;
  bf16x8 av[2][8];   // double-buffered A fragment sets (static indices only)

  // ---- prologue ----
  // gates/bias -> LDS first (isolated vmcnt(0), once)
  {
    float gt[4], bt[4];
    #pragma unroll
    for (int i = 0; i < 4; ++i) {
      int idx = i * 256 + tid;
      gt[i] = gates[(size_t)(brow0 + (idx & 127)) * 16 + mb + (idx >> 7)];
      bt[i] = bias[(size_t)(mb + (idx >> 7)) * 1024 + ncol0 + (idx & 127)];
    }
    asm volatile("s_waitcnt vmcnt(0)" ::: "memory");
    #pragma unroll
    for (int i = 0; i < 4; ++i) {
      int idx = i * 256 + tid;
      lgat[idx] = gt[i];
      lbias[idx] = bt[i];
    }
  }
  // GLL B(0)->b0, B(1)->b1, then A(0) -> av[0]
  GLL(bsrc + sg[0], b0 + ldd[0]); GLL(bsrc + sg[1], b0 + ldd[1]);
  GLL(bsrc + sg[2], b0 + ldd[2]); GLL(bsrc + sg[3], b0 + ldd[3]);
  GLL(bsrc + 64 + sg[0], b1 + ldd[0]); GLL(bsrc + 64 + sg[1], b1 + ldd[1]);
  GLL(bsrc + 64 + sg[2], b1 + ldd[2]); GLL(bsrc + 64 + sg[3], b1 + ldd[3]);
  __builtin_amdgcn_sched_barrier(0);
  av[0][0] = *(const bf16x8*)(ab0); av[0][4] = *(const bf16x8*)(ab0 + 512);
  av[0][1] = *(const bf16x8*)(ab1); av[0][5] = *(const bf16x8*)(ab1 + 512);
  av[0][2] = *(const bf16x8*)(ab2); av[0][6] = *(const bf16x8*)(ab2 + 512);
  av[0][3] = *(const bf16x8*)(ab3); av[0][7] = *(const bf16x8*)(ab3 + 512);
  // drain B(0) (oldest 4): keep B(1)+A(0) = 12 in flight
  asm volatile("s_waitcnt vmcnt(12)" ::: "memory");
  __builtin_amdgcn_s_barrier();
  __builtin_amdgcn_sched_barrier(0);

  // ---- main loop: x2 unrolled for static A-set alternation; tiles 0..125 full pipeline ----
  for (int u = 0; u < NT / 2 - 1; ++u) {
    SUBITER(2 * u,     0, 1, true, true);
    SUBITER(2 * u + 1, 1, 0, true, true);
  }
  SUBITER(NT - 2, 0, 1, false, true);
  SUBITER(NT - 1, 1, 0, false, false);

  float* op = grp ? p1out : out0;
  #pragma unroll
  for (int mi = 0; mi < 4; ++mi)
    #pragma unroll
    for (int j = 0; j < 4; ++j) {
      int row = brow0 + wm * 64 + mi * 16 + lk * 4 + j;
      #pragma unroll
      for (int ni = 0; ni < 4; ++ni) {
        int col = ncol0 + wn * 64 + ni * 16 + lrow;
        op[(size_t)row * 1024 + col] = oacc[mi][ni][j];
      }
    }
}

// ---- kernel 5: out += p1 ----
__global__ __launch_bounds__(256) void k_add(float* __restrict__ out, const float* __restrict__ p1) {
  int i = blockIdx.x * 256 + threadIdx.x;
  f32x4 a = ((const f32x4*)out)[i];
  f32x4 b = ((const f32x4*)p1)[i];
  ((f32x4*)out)[i] = a + b;
}

extern "C" void kernel_launch(void* const* d_in, const int* in_sizes, int n_in,
                              void* d_out, int out_size, void* d_ws, size_t ws_size,
                              hipStream_t stream) {
  const float* x  = (const float*)d_in[0];   // [4096][1024]
  const float* W  = (const float*)d_in[1];   // [16][1024][1024]
  const float* b  = (const float*)d_in[2];   // [16][1024]
  const float* Wg = (const float*)d_in[3];   // [1024][16]
  const float* bg = (const float*)d_in[4];   // [16]
  float* out = (float*)d_out;                // [4096][1024]

  char* ws = (char*)d_ws;
  u16* xb2    = (u16*)ws;                      // 8,388,608 B (fragment-major)
  u16* wt     = (u16*)(ws + 8388608);          // 33,554,432 B
  float* gts  = (float*)(ws + 41943040);       // 262,144 B
  float* p1   = (float*)(ws + 42205184);       // 16,777,216 B

  k_cvt_x2<<<2048, 256, 0, stream>>>(x, xb2);
  k_tw<<<4096, 256, 0, stream>>>(W, wt);
  k_gates<<<1024, 256, 0, stream>>>(x, Wg, bg, gts);
  k_moe<<<512, 256, 0, stream>>>(xb2, wt, gts, b, out, p1);
  k_add<<<4096, 256, 0, stream>>>(out, p1);
}